// Round 9
// baseline (1019.370 us; speedup 1.0000x reference)
//
#include <hip/hip_runtime.h>
#include <hip/hip_fp16.h>

// B=2048 rows, T=2048 steps, H=32. Wave = ONE batch row; lane = (k, gp).
// gp0 owns gates {i,f}, gp1 owns {g,o}, full 32-wide contraction each, no
// cross-lane reduce (R8-verified). NEW in R9: ZERO LDS in the step loop.
//  - h broadcast: own h -> f16 (1 cvt), 32 v_readlane -> SGPRs, 16 scalar
//    packs -> 16 wave-uniform packed-f16 dwords; fdot2 reads h as its one
//    SGPR operand. Readlanes are independent (pipelined) vs the ~150-250cyc
//    in-order ds_write->ds_read round trip they replace.
//  - x: 8-step double-buffered register prefetch (wave-uniform addresses).
// Cross-gate exchange via permlane32_swap, split activations, paired stores:
// all carried over from R8 (passed, absmax 9.8e-4).

#define Bsz 2048
#define Tsz 2048
#define Hsz 32

typedef _Float16 v2h __attribute__((ext_vector_type(2)));

__device__ __forceinline__ float fast_rcp(float x) { return __builtin_amdgcn_rcpf(x); }
__device__ __forceinline__ float fast_exp2(float x) { return __builtin_amdgcn_exp2f(x); }

// h-operand (uniform/SGPR) x weight-operand (VGPR) packed-f16 dot
__device__ __forceinline__ float fdot2u(unsigned hs, unsigned wv, float c) {
#if __has_builtin(__builtin_amdgcn_fdot2)
    return __builtin_amdgcn_fdot2(__builtin_bit_cast(v2h, hs),
                                  __builtin_bit_cast(v2h, wv), c, false);
#else
    v2h a = __builtin_bit_cast(v2h, hs), b = __builtin_bit_cast(v2h, wv);
    return __fmaf_rn((float)a.x, (float)b.x,
                     __fmaf_rn((float)a.y, (float)b.y, c));
#endif
}

// r0 = low-half-origin values (in all lanes), r1 = high-half-origin values.
__device__ __forceinline__ void plswap(float a, float b, float& r0, float& r1) {
#if __has_builtin(__builtin_amdgcn_permlane32_swap)
    auto r = __builtin_amdgcn_permlane32_swap(__float_as_uint(a), __float_as_uint(b),
                                              false, false);
    r0 = __uint_as_float(r[0]);
    r1 = __uint_as_float(r[1]);
#else
    const bool hi = (threadIdx.x & 32) != 0;
    r0 = hi ? __shfl_xor(b, 32) : a;
    r1 = hi ? b : __shfl_xor(a, 32);
#endif
}

__global__ __launch_bounds__(256, 2) void lstm_fwd_kernel(
    const float* __restrict__ x,      // (B, T)
    const float* __restrict__ w_ih,   // (4H, 1)
    const float* __restrict__ w_hh,   // (4H, H)
    const float* __restrict__ b_ih,   // (4H,)
    const float* __restrict__ b_hh,   // (4H,)
    float* __restrict__ out)          // (B, T*H)
{
    const int lane = threadIdx.x & 63;
    const int k    = lane & 31;
    const int gp   = lane >> 5;           // 0: gates {i,f} ; 1: gates {g,o}
    const int wv   = __builtin_amdgcn_readfirstlane((int)(threadIdx.x >> 6));
    const int b    = blockIdx.x * 4 + wv;

    // ---- f16 weights: rows jA = 64*gp + k (i|g), jB = jA + 32 (f|o) ----
    unsigned WA[16], WB[16];
    {
        const float* rA = w_hh + (size_t)(gp * 64 + k) * 32;
        const float* rB = rA + 32 * 32;
#pragma unroll
        for (int j = 0; j < 16; ++j) {
            WA[j] = __builtin_bit_cast(
                unsigned, (v2h){(_Float16)rA[2 * j], (_Float16)rA[2 * j + 1]});
            WB[j] = __builtin_bit_cast(
                unsigned, (v2h){(_Float16)rB[2 * j], (_Float16)rB[2 * j + 1]});
        }
    }
    const int jA = gp * 64 + k, jB = jA + 32;
    const float wiA = w_ih[jA], bsA = b_ih[jA] + b_hh[jA];
    const float wiB = w_ih[jB], bsB = b_ih[jB] + b_hh[jB];

    // unified activation: a1 = A1*rcp(1+exp2(B1*p)) + C1
    // gp0 -> sigmoid(i), gp1 -> tanh(g); second value always sigmoid
    const float B1 = gp ? -2.885390082f : -1.442695041f;
    const float A1 = gp ? 2.0f : 1.0f;
    const float C1 = gp ? -1.0f : 0.0f;

    float c = 0.0f, h = 0.0f, hprev = 0.0f;

    const float* xrow = x + (size_t)b * Tsz;
    float* op = out + (size_t)b * (size_t)(Tsz * Hsz) + gp * 32 + k;

    float xc[8], xn[8];
#pragma unroll
    for (int j = 0; j < 8; ++j) xc[j] = xrow[j];

#pragma unroll 1
    for (int t0 = 0; t0 < Tsz; t0 += 8) {
        const int tn = (t0 + 8 < Tsz) ? (t0 + 8) : t0;  // clamped (dead last)
#pragma unroll
        for (int j = 0; j < 8; ++j) xn[j] = xrow[tn + j];

#pragma unroll
        for (int u = 0; u < 8; ++u) {
            // ---- h all-gather: cvt + 32 readlane + 16 scalar packs ----
            const unsigned hbits =
                (unsigned)__builtin_bit_cast(unsigned short, (_Float16)h);
            unsigned hp[16];
#pragma unroll
            for (int m = 0; m < 16; ++m) {
                unsigned lo = (unsigned)__builtin_amdgcn_readlane((int)hbits, 2 * m);
                unsigned hi = (unsigned)__builtin_amdgcn_readlane((int)hbits, 2 * m + 1);
                hp[m] = (lo & 0xffffu) | (hi << 16);
            }

            // ---- 4 independent 8-deep dot chains (2 per owned gate) ----
            float sA0 = 0.f, sA1 = 0.f, sB0 = 0.f, sB1 = 0.f;
#pragma unroll
            for (int m = 0; m < 8; ++m) {
                sA0 = fdot2u(hp[m], WA[m], sA0);
                sB0 = fdot2u(hp[m], WB[m], sB0);
            }
#pragma unroll
            for (int m = 8; m < 16; ++m) {
                sA1 = fdot2u(hp[m], WA[m], sA1);
                sB1 = fdot2u(hp[m], WB[m], sB1);
            }
            const float xt = xc[u];
            const float pA = (sA0 + sA1) + __fmaf_rn(wiA, xt, bsA);
            const float pB = (sB0 + sB1) + __fmaf_rn(wiB, xt, bsB);

            // own-pair activations
            const float a1 = __fmaf_rn(A1, fast_rcp(1.0f + fast_exp2(B1 * pA)), C1);
            const float a2 = fast_rcp(1.0f + fast_exp2(-1.442695041f * pB));

            float i_, g_, f_, o_;
            plswap(a1, a1, i_, g_);   // i_ = sig(i), g_ = tanh(g), all lanes
            plswap(a2, a2, f_, o_);   // f_ = sig(f), o_ = sig(o), all lanes

            c = __fmaf_rn(f_, c, i_ * g_);
            const float th =
                __fmaf_rn(2.0f, fast_rcp(1.0f + fast_exp2(-2.885390082f * c)), -1.0f);
            h = o_ * th;

            if (u & 1) {              // paired store: rows t-1 (gp0), t (gp1)
                *op = gp ? h : hprev;
                op += 64;
            } else {
                hprev = h;
            }
        }
#pragma unroll
        for (int j = 0; j < 8; ++j) xc[j] = xn[j];
    }
}

extern "C" void kernel_launch(void* const* d_in, const int* in_sizes, int n_in,
                              void* d_out, int out_size, void* d_ws, size_t ws_size,
                              hipStream_t stream) {
    const float* x    = (const float*)d_in[0];
    const float* w_ih = (const float*)d_in[1];
    const float* w_hh = (const float*)d_in[2];
    const float* b_ih = (const float*)d_in[3];
    const float* b_hh = (const float*)d_in[4];
    float* out = (float*)d_out;

    dim3 grid(Bsz / 4);   // 512 blocks = 2 per CU -> 2 waves/SIMD
    dim3 block(256);      // 4 waves, each = one batch row (32 k x 2 gate-pairs)
    lstm_fwd_kernel<<<grid, block, 0, stream>>>(x, w_ih, w_hh, b_ih, b_hh, out);
}

// Round 10
// 690.554 us; speedup vs baseline: 1.4762x; 1.4762x over previous
//
#include <hip/hip_runtime.h>
#include <hip/hip_fp16.h>

// B=2048 rows, T=2048 steps, H=32. Wave = ONE batch row; lane = (k, gp).
// gp0 owns gates {i,f}, gp1 owns {g,o} (R8-verified datapath). NEW in R10:
// the h-exchange is 100% VALU -- zero LDS anywhere:
//   h -> cvt f16 -> permlane16_swap (pairs h[m] with h[m+16]) -> pack ->
//   15x v_mov_dpp row_ror:N (rotations within 16-lane rows enumerate all
//   16 packed k-pairs, each a depth-1 fan-out from D0).
// Semantics are SELF-CALIBRATED: at init the lane-id is pushed through the
// identical pipeline; the resulting per-lane indices drive the weight
// gather-pack, so any swap-order/rotation-direction misread cancels.
// Side effect: weight loads are data-dependent gathers -> not remat-able ->
// the compiler must keep W resident. x: register prefetch (R9-proven part).

#define Bsz 2048
#define Tsz 2048
#define Hsz 32

typedef _Float16 v2h __attribute__((ext_vector_type(2)));

__device__ __forceinline__ float fast_rcp(float x) { return __builtin_amdgcn_rcpf(x); }
__device__ __forceinline__ float fast_exp2(float x) { return __builtin_amdgcn_exp2f(x); }

__device__ __forceinline__ float fdot2u(unsigned a, unsigned b, float c) {
#if __has_builtin(__builtin_amdgcn_fdot2)
    return __builtin_amdgcn_fdot2(__builtin_bit_cast(v2h, a),
                                  __builtin_bit_cast(v2h, b), c, false);
#else
    v2h av = __builtin_bit_cast(v2h, a), bv = __builtin_bit_cast(v2h, b);
    return __fmaf_rn((float)av.x, (float)bv.x,
                     __fmaf_rn((float)av.y, (float)bv.y, c));
#endif
}

// xor-32 exchange; r0 = low-half-origin value (all lanes), r1 = high-half.
__device__ __forceinline__ void plswap(float a, float b, float& r0, float& r1) {
#if __has_builtin(__builtin_amdgcn_permlane32_swap)
    auto r = __builtin_amdgcn_permlane32_swap(__float_as_uint(a), __float_as_uint(b),
                                              false, false);
    r0 = __uint_as_float(r[0]);
    r1 = __uint_as_float(r[1]);
#else
    const bool hi = (threadIdx.x & 32) != 0;
    r0 = hi ? __shfl_xor(b, 32) : a;
    r1 = hi ? b : __shfl_xor(a, 32);
#endif
}

// xor-16 exchange on dwords; r0 = bit4==0-origin, r1 = bit4==1-origin.
__device__ __forceinline__ void pl16(unsigned a, unsigned b, unsigned& r0, unsigned& r1) {
#if __has_builtin(__builtin_amdgcn_permlane16_swap)
    auto r = __builtin_amdgcn_permlane16_swap(a, b, false, false);
    r0 = r[0];
    r1 = r[1];
#else
    const bool hi = (threadIdx.x & 16) != 0;
    r0 = hi ? (unsigned)__shfl_xor((int)a, 16) : a;
    r1 = hi ? b : (unsigned)__shfl_xor((int)b, 16);
#endif
}

template <int N>
__device__ __forceinline__ unsigned ror16(unsigned v) {
    if constexpr (N == 0) return v;
    else
        return (unsigned)__builtin_amdgcn_mov_dpp((int)v, 0x120 + N, 0xf, 0xf, false);
}

__device__ __forceinline__ unsigned pkh(float a, float b) {
    unsigned ua = (unsigned)__builtin_bit_cast(unsigned short, (_Float16)a);
    unsigned ub = (unsigned)__builtin_bit_cast(unsigned short, (_Float16)b);
    return ua | (ub << 16);
}

__global__ __launch_bounds__(256, 2) void lstm_fwd_kernel(
    const float* __restrict__ x,      // (B, T)
    const float* __restrict__ w_ih,   // (4H, 1)
    const float* __restrict__ w_hh,   // (4H, H)
    const float* __restrict__ b_ih,   // (4H,)
    const float* __restrict__ b_hh,   // (4H,)
    float* __restrict__ out)          // (B, T*H)
{
    const int lane = threadIdx.x & 63;
    const int k    = lane & 31;
    const int gp   = lane >> 5;           // 0: gates {i,f} ; 1: gates {g,o}
    const int wv   = __builtin_amdgcn_readfirstlane((int)(threadIdx.x >> 6));
    const int b    = blockIdx.x * 4 + wv;

    // ---- self-calibration probe: where does the gather pipeline put data?
    // Runtime: hf16 -> pl16 -> pack -> ror16<d>. Probe: lane-id through the
    // SAME ops; pd[d] then holds (src_lane_lo, src_lane_hi) for dword d.
    unsigned pa, pb;
    pl16((unsigned)lane, (unsigned)lane, pa, pb);
    const unsigned probe0 = (pa & 0xffffu) | (pb << 16);
    unsigned pd[16];
    pd[0]  = probe0;
    pd[1]  = ror16<1>(probe0);   pd[2]  = ror16<2>(probe0);
    pd[3]  = ror16<3>(probe0);   pd[4]  = ror16<4>(probe0);
    pd[5]  = ror16<5>(probe0);   pd[6]  = ror16<6>(probe0);
    pd[7]  = ror16<7>(probe0);   pd[8]  = ror16<8>(probe0);
    pd[9]  = ror16<9>(probe0);   pd[10] = ror16<10>(probe0);
    pd[11] = ror16<11>(probe0);  pd[12] = ror16<12>(probe0);
    pd[13] = ror16<13>(probe0);  pd[14] = ror16<14>(probe0);
    pd[15] = ror16<15>(probe0);

    // ---- weights, gather-packed to match the runtime h-dword layout ----
    // lane m holds h[m&31], so dword d pairs k-indices (pd[d]&31, pd[d]>>16 &31)
    const int jA = gp * 64 + k, jB = jA + 32;   // i|g row, f|o row
    const float* rA = w_hh + (size_t)jA * Hsz;
    const float* rB = w_hh + (size_t)jB * Hsz;
    unsigned WA[16], WB[16];
#pragma unroll
    for (int d = 0; d < 16; ++d) {
        const int ia = (int)(pd[d] & 31u);
        const int ib = (int)((pd[d] >> 16) & 31u);
        WA[d] = pkh(rA[ia], rA[ib]);
        WB[d] = pkh(rB[ia], rB[ib]);
    }
    const float wiA = w_ih[jA], bsA = b_ih[jA] + b_hh[jA];
    const float wiB = w_ih[jB], bsB = b_ih[jB] + b_hh[jB];

    // unified activation: a1 = A1*rcp(1+exp2(B1*p)) + C1
    // gp0 -> sigmoid(i), gp1 -> tanh(g); second value always sigmoid
    const float B1 = gp ? -2.885390082f : -1.442695041f;
    const float A1 = gp ? 2.0f : 1.0f;
    const float C1 = gp ? -1.0f : 0.0f;

    float c = 0.0f, h = 0.0f, hprev = 0.0f;

    const float* xrow = x + (size_t)b * Tsz;
    float* op = out + (size_t)b * (size_t)(Tsz * Hsz) + gp * 32 + k;

    float xc[8], xn[8];
#pragma unroll
    for (int j = 0; j < 8; ++j) xc[j] = xrow[j];

#pragma unroll 1
    for (int t0 = 0; t0 < Tsz; t0 += 8) {
        const int tn = (t0 + 8 < Tsz) ? (t0 + 8) : t0;  // clamped (dead last)
#pragma unroll
        for (int j = 0; j < 8; ++j) xn[j] = xrow[tn + j];

#pragma unroll
        for (int u = 0; u < 8; ++u) {
            // ---- all-VALU h gather: cvt + pl16 + pack + 15 dpp rotations ----
            const unsigned hbits =
                (unsigned)__builtin_bit_cast(unsigned short, (_Float16)h);
            unsigned ra, rb;
            pl16(hbits, hbits, ra, rb);
            const unsigned D0 = (ra & 0xffffu) | (rb << 16);
            unsigned D[16];
            D[0]  = D0;
            D[1]  = ror16<1>(D0);   D[2]  = ror16<2>(D0);
            D[3]  = ror16<3>(D0);   D[4]  = ror16<4>(D0);
            D[5]  = ror16<5>(D0);   D[6]  = ror16<6>(D0);
            D[7]  = ror16<7>(D0);   D[8]  = ror16<8>(D0);
            D[9]  = ror16<9>(D0);   D[10] = ror16<10>(D0);
            D[11] = ror16<11>(D0);  D[12] = ror16<12>(D0);
            D[13] = ror16<13>(D0);  D[14] = ror16<14>(D0);
            D[15] = ror16<15>(D0);

            // ---- 4 independent 8-deep dot chains (2 per owned gate) ----
            float sA0 = 0.f, sA1 = 0.f, sB0 = 0.f, sB1 = 0.f;
#pragma unroll
            for (int m = 0; m < 8; ++m) {
                sA0 = fdot2u(D[m], WA[m], sA0);
                sB0 = fdot2u(D[m], WB[m], sB0);
            }
#pragma unroll
            for (int m = 8; m < 16; ++m) {
                sA1 = fdot2u(D[m], WA[m], sA1);
                sB1 = fdot2u(D[m], WB[m], sB1);
            }
            const float xt = xc[u];
            const float pA = (sA0 + sA1) + __fmaf_rn(wiA, xt, bsA);
            const float pB = (sB0 + sB1) + __fmaf_rn(wiB, xt, bsB);

            // own-pair activations
            const float a1 = __fmaf_rn(A1, fast_rcp(1.0f + fast_exp2(B1 * pA)), C1);
            const float a2 = fast_rcp(1.0f + fast_exp2(-1.442695041f * pB));

            float i_, g_, f_, o_;
            plswap(a1, a1, i_, g_);   // i_ = sig(i), g_ = tanh(g), all lanes
            plswap(a2, a2, f_, o_);   // f_ = sig(f), o_ = sig(o), all lanes

            c = __fmaf_rn(f_, c, i_ * g_);
            const float th =
                __fmaf_rn(2.0f, fast_rcp(1.0f + fast_exp2(-2.885390082f * c)), -1.0f);
            h = o_ * th;

            if (u & 1) {              // paired store: rows t-1 (gp0), t (gp1)
                *op = gp ? h : hprev;
                op += 64;
            } else {
                hprev = h;
            }
        }
#pragma unroll
        for (int j = 0; j < 8; ++j) xc[j] = xn[j];
    }
}

extern "C" void kernel_launch(void* const* d_in, const int* in_sizes, int n_in,
                              void* d_out, int out_size, void* d_ws, size_t ws_size,
                              hipStream_t stream) {
    const float* x    = (const float*)d_in[0];
    const float* w_ih = (const float*)d_in[1];
    const float* w_hh = (const float*)d_in[2];
    const float* b_ih = (const float*)d_in[3];
    const float* b_hh = (const float*)d_in[4];
    float* out = (float*)d_out;

    dim3 grid(Bsz / 4);   // 512 blocks = 2 per CU -> 2 waves/SIMD
    dim3 block(256);      // 4 waves, each = one batch row (32 k x 2 gate-pairs)
    lstm_fwd_kernel<<<grid, block, 0, stream>>>(x, w_ih, w_hh, b_ih, b_hh, out);
}